// Round 1
// baseline (294.707 us; speedup 1.0000x reference)
//
#include <hip/hip_runtime.h>

// Problem constants (from reference setup_inputs): B=256, NT=301, D=96, NSEG=50
// linspace(1,301,51) -> exact multiples of 6 + 1, so segment s = rows [6s, 6s+6].
#define BB 256
#define NT 301
#define DD 96
#define NSEG 50
#define SEGROWS 7
#define NTRI (DD * (DD - 1) / 2)   // 4560
#define OUTD (DD + NTRI)           // 4656

__global__ __launch_bounds__(256)
void logsig_kernel(const float* __restrict__ inp, float* __restrict__ out) {
    const int bs = blockIdx.x;          // 0 .. B*NSEG-1
    const int b  = bs / NSEG;
    const int s  = bs % NSEG;

    __shared__ float seg[SEGROWS * DD]; // 7 x 96 floats, contiguous in global

    const float* src = inp + ((size_t)b * NT + (size_t)6 * s) * DD;
    for (int idx = threadIdx.x; idx < SEGROWS * DD; idx += 256)
        seg[idx] = src[idx];
    __syncthreads();

    float* o = out + (size_t)bs * OUTD;

    // lvl1: seg[last] - seg[first]
    if (threadIdx.x < DD)
        o[threadIdx.x] = seg[6 * DD + threadIdx.x] - seg[threadIdx.x];

    const int ty = threadIdx.x >> 4;    // 0..15 (row within 16x16 tile)
    const int tx = threadIdx.x & 15;    // 0..15 (col within tile)

    for (int ti = 0; ti < 6; ++ti) {
        const int i = 16 * ti + ty;
        float si[SEGROWS];
        #pragma unroll
        for (int t = 0; t < SEGROWS; ++t) si[t] = seg[t * DD + i];

        for (int tj = ti; tj < 6; ++tj) {
            const int j = 16 * tj + tx;
            if (j > i) {
                float sj[SEGROWS];
                #pragma unroll
                for (int t = 0; t < SEGROWS; ++t) sj[t] = seg[t * DD + j];

                // A_ij = 0.5 * sum_{t=1..5} [(s_i[t]-s_i[0])(s_j[t+1]-s_j[t])
                //                          - (s_j[t]-s_j[0])(s_i[t+1]-s_i[t])]
                float acc = 0.f;
                #pragma unroll
                for (int t = 1; t < 6; ++t) {
                    const float xpi = si[t] - si[0];
                    const float dxj = sj[t + 1] - sj[t];
                    const float xpj = sj[t] - sj[0];
                    const float dxi = si[t + 1] - si[t];
                    acc += xpi * dxj - xpj * dxi;
                }
                // linear index into triu(k=1), row-major: row i starts at i*(2D-1-i)/2
                const int tri = i * (2 * DD - 1 - i) / 2 + (j - i - 1);
                o[DD + tri] = 0.5f * acc;
            }
        }
    }
}

extern "C" void kernel_launch(void* const* d_in, const int* in_sizes, int n_in,
                              void* d_out, int out_size, void* d_ws, size_t ws_size,
                              hipStream_t stream) {
    const float* inp = (const float*)d_in[0];
    float* out = (float*)d_out;
    logsig_kernel<<<BB * NSEG, 256, 0, stream>>>(inp, out);
}